// Round 4
// baseline (229.937 us; speedup 1.0000x reference)
//
#include <hip/hip_runtime.h>

typedef __attribute__((ext_vector_type(8))) short bf16x8;
typedef __attribute__((ext_vector_type(4))) float f32x4;

#define NB    4096
#define NLINK 33
#define NJ    32
#define KTOT  1024
#define CJ    128

// Pre-converted, fragment-swizzled bf16 W (8.4 MB), rebuilt every call.
// Cell ((j*32 + kt)*128 + c)*4 + q  holds bf16x8 of W[j][kt*32 + q*8 + e][c].
// (Layout correctness-verified R2/R3.)
__device__ short g_Wf[NJ * KTOT * CJ];

// round-to-nearest-even f32 -> bf16 (finite inputs)
static __device__ __forceinline__ short f2bf(float f) {
    unsigned u = __builtin_bit_cast(unsigned, f);
    unsigned r = u + 0x7FFFu + ((u >> 16) & 1u);
    return (short)(r >> 16);
}

__global__ __launch_bounds__(256) void conv_w(const float* __restrict__ W) {
    const int gid = blockIdx.x * 256 + threadIdx.x;   // destination cell index
    const int q  = gid & 3;
    const int c  = (gid >> 2) & 127;
    const int kt = (gid >> 9) & 31;
    const int j  = gid >> 14;
    const float* src = W + ((size_t)j * KTOT + kt * 32 + q * 8) * CJ + c;
    bf16x8 v;
    #pragma unroll
    for (int e = 0; e < 8; ++e) v[e] = f2bf(src[(size_t)e * CJ]);
    reinterpret_cast<bf16x8*>(g_Wf)[gid] = v;
}

// Barrier-free grouped GEMM. One wave owns 16 rows x 128 cols.
// A-loads batched 4 K-steps at a time -> 512B contiguous DRAM bursts per row.
__global__ __launch_bounds__(256, 2) void joint_gemm(
    const float* __restrict__ link,
    const float* __restrict__ jf,
    const float* __restrict__ bias,
    const int*   __restrict__ child,
    float* __restrict__ out)
{
    const int tid  = threadIdx.x;
    const int wave = tid >> 6;       // 0..3
    const int q    = (tid >> 4) & 3; // k-subgroup
    const int r    = tid & 15;       // row-within-16 / col-within-16

    const int bx = blockIdx.x;
    const int j  = bx & 31;          // j-minor: same-j blocks share an XCD L2 (W panel 1MB/XCD)
    const int mt = bx >> 5;
    const int cidx = child[j];

    const int arow_idx = mt * 64 + wave * 16 + r;
    const float* arow = link + ((size_t)arow_idx * NLINK + cidx) * KTOT + q * 8;

    const bf16x8* wb = reinterpret_cast<const bf16x8*>(g_Wf);
    const size_t bb = (size_t)j * 16384 + r * 4 + q;

    f32x4  acc[8] = {};        // 16 rows x 128 cols
    float4 Ab[2][8];           // two 4-step A batches (8 f32/step/lane)

    // prologue: batches 0 and 1 (each: 16 rows x 512B contiguous per row)
    #pragma unroll
    for (int i = 0; i < 4; ++i) {
        const float4* p = reinterpret_cast<const float4*>(arow + i * 32);
        Ab[0][i * 2] = p[0]; Ab[0][i * 2 + 1] = p[1];
    }
    #pragma unroll
    for (int i = 0; i < 4; ++i) {
        const float4* p = reinterpret_cast<const float4*>(arow + 128 + i * 32);
        Ab[1][i * 2] = p[0]; Ab[1][i * 2 + 1] = p[1];
    }

    #pragma unroll
    for (int g = 0; g < 8; ++g) {              // 8 groups x 4 K-steps = K 1024
        #pragma unroll
        for (int i = 0; i < 4; ++i) {
            const int t = g * 4 + i;
            bf16x8 Breg[8];
            #pragma unroll
            for (int ni = 0; ni < 8; ++ni)
                Breg[ni] = wb[bb + (size_t)t * 512 + ni * 64];   // L2 hits
            const float4 a0 = Ab[g & 1][i * 2];
            const float4 a1 = Ab[g & 1][i * 2 + 1];
            bf16x8 af;
            af[0] = f2bf(a0.x); af[1] = f2bf(a0.y); af[2] = f2bf(a0.z); af[3] = f2bf(a0.w);
            af[4] = f2bf(a1.x); af[5] = f2bf(a1.y); af[6] = f2bf(a1.z); af[7] = f2bf(a1.w);
            #pragma unroll
            for (int ni = 0; ni < 8; ++ni)
                acc[ni] = __builtin_amdgcn_mfma_f32_16x16x32_bf16(af, Breg[ni], acc[ni], 0, 0, 0);
        }
        if (g + 2 < 8) {                        // refill consumed batch, 2 groups ahead
            #pragma unroll
            for (int i = 0; i < 4; ++i) {
                const float4* p = reinterpret_cast<const float4*>(arow + (g + 2) * 128 + i * 32);
                Ab[g & 1][i * 2] = p[0]; Ab[g & 1][i * 2 + 1] = p[1];
            }
        }
    }

    // epilogue: + bias + joint_feats
    float bv[8];
    #pragma unroll
    for (int ni = 0; ni < 8; ++ni) bv[ni] = bias[j * CJ + ni * 16 + r];

    #pragma unroll
    for (int rr = 0; rr < 4; ++rr) {
        const int brow = mt * 64 + wave * 16 + q * 4 + rr;
        const size_t ob = ((size_t)brow * NJ + j) * CJ;
        #pragma unroll
        for (int ni = 0; ni < 8; ++ni) {
            const int o = ni * 16 + r;
            out[ob + o] = acc[ni][rr] + bv[ni] + jf[ob + o];
        }
    }
}

extern "C" void kernel_launch(void* const* d_in, const int* in_sizes, int n_in,
                              void* d_out, int out_size, void* d_ws, size_t ws_size,
                              hipStream_t stream) {
    (void)in_sizes; (void)n_in; (void)out_size; (void)d_ws; (void)ws_size;
    const float* link  = (const float*)d_in[0];
    const float* jfeat = (const float*)d_in[1];
    const float* W     = (const float*)d_in[2];
    const float* bias  = (const float*)d_in[3];
    const int*   child = (const int*)d_in[4];
    float* out = (float*)d_out;

    conv_w<<<dim3((NJ * KTOT * CJ / 8) / 256), dim3(256), 0, stream>>>(W);
    joint_gemm<<<dim3(NJ * (NB / 64)), dim3(256), 0, stream>>>(link, jfeat, bias, child, out);
}

// Round 5
// 173.641 us; speedup vs baseline: 1.3242x; 1.3242x over previous
//
#include <hip/hip_runtime.h>

typedef __attribute__((ext_vector_type(8))) short bf16x8;
typedef __attribute__((ext_vector_type(4))) short bf16x4;
typedef __attribute__((ext_vector_type(4))) float f32x4;

#define NB    4096
#define NLINK 33
#define NJ    32
#define KTOT  1024
#define CJ    128
#define BM    32
#define BKF   256              // K-floats per macro-tile (1KB per row per touch)
#define NMAC  (KTOT / BKF)     // 4 macros

// Pre-converted, fragment-swizzled bf16 W (8.4 MB), rebuilt every call.
// Cell ((j*32 + kt)*128 + c)*4 + q holds bf16x8 of W[j][kt*32 + q*8 + e][c].
// (Layout correctness-verified R2-R4.)
__device__ short g_Wf[NJ * KTOT * CJ];

// round-to-nearest-even f32 -> bf16 (finite inputs)
static __device__ __forceinline__ short f2bf(float f) {
    unsigned u = __builtin_bit_cast(unsigned, f);
    unsigned r = u + 0x7FFFu + ((u >> 16) & 1u);
    return (short)(r >> 16);
}

__global__ __launch_bounds__(256) void conv_w(const float* __restrict__ W) {
    const int gid = blockIdx.x * 256 + threadIdx.x;
    const int q  = gid & 3;
    const int c  = (gid >> 2) & 127;
    const int kt = (gid >> 9) & 31;
    const int j  = gid >> 14;
    const float* src = W + ((size_t)j * KTOT + kt * 32 + q * 8) * CJ + c;
    bf16x8 v;
    #pragma unroll
    for (int e = 0; e < 8; ++e) v[e] = f2bf(src[(size_t)e * CJ]);
    reinterpret_cast<bf16x8*>(g_Wf)[gid] = v;
}

// Block = 32 batch rows x 1 joint x 128 cols. A staged 1KB-per-row-per-touch.
__global__ __launch_bounds__(256, 3) void joint_gemm(
    const float* __restrict__ link,
    const float* __restrict__ jf,
    const float* __restrict__ bias,
    const int*   __restrict__ child,
    float* __restrict__ out)
{
    // fragment-ready: cell (kc 0..31, row 0..31) = bf16x8 of floats [kc*8, kc*8+8)
    __shared__ short lA[BM * BKF];   // 16 KB

    const int tid  = threadIdx.x;
    const int lane = tid & 63;
    const int wave = tid >> 6;       // col quarter (32 cols)
    const int q    = lane >> 4;      // 0..3
    const int r    = lane & 15;      // 0..15

    const int bx = blockIdx.x;
    const int j  = bx & 31;          // j-minor: 4 joints/XCD -> 1MB W panel in L2
    const int mt = bx >> 5;
    const int row0 = mt * BM;
    const int cidx = child[j];

    // staging: thread = (srow, li); load i covers floats [4*li + 32*i, +4)
    const int srow = tid >> 3;       // 0..31
    const int li   = tid & 7;        // 0..7
    const float* abase = link + ((size_t)(row0 + srow) * NLINK + cidx) * KTOT + 4 * li;
    // LDS dest for load i: cell kc = (li>>1) + 4*i, half = li&1
    short* lw0 = lA + (((li >> 1) * 32 + srow) * 8 + (li & 1) * 4);

    const bf16x8* wb = reinterpret_cast<const bf16x8*>(g_Wf);
    const size_t bb = ((size_t)j * 32 * 128 + wave * 32 + r) * 4 + q;  // + kt*512 + ni*64

    f32x4  acc[2][2] = {};
    float4 Ar[8];                    // A prefetch: 8 x 16B = row's 1KB / 8 threads

    auto loadA = [&](int m) {
        #pragma unroll
        for (int i = 0; i < 8; ++i)
            Ar[i] = *reinterpret_cast<const float4*>(abase + m * BKF + 32 * i);
    };

    loadA(0);

    for (int m = 0; m < NMAC; ++m) {
        __syncthreads();             // previous compute done reading lA
        #pragma unroll
        for (int i = 0; i < 8; ++i) {   // stage: f32 regs -> bf16 -> LDS
            bf16x4 v;
            v[0] = f2bf(Ar[i].x); v[1] = f2bf(Ar[i].y);
            v[2] = f2bf(Ar[i].z); v[3] = f2bf(Ar[i].w);
            *reinterpret_cast<bf16x4*>(lw0 + i * 1024) = v;  // +4 cells per i
        }
        __syncthreads();             // tile ready

        // B first (oldest in VMEM FIFO), then A for m+1 (newest) -> consuming B
        // via partial vmcnt never drains the A prefetch.
        bf16x8 Ball[16];
        #pragma unroll
        for (int ks = 0; ks < 8; ++ks) {
            Ball[2 * ks]     = wb[bb + (size_t)(m * 8 + ks) * 512];
            Ball[2 * ks + 1] = wb[bb + (size_t)(m * 8 + ks) * 512 + 64];
        }
        if (m + 1 < NMAC) loadA(m + 1);   // HBM loads in flight through compute

        #pragma unroll
        for (int ks = 0; ks < 8; ++ks) {
            const short* cb = lA + ((ks * 4 + q) * 32 + r) * 8;
            bf16x8 a0 = *reinterpret_cast<const bf16x8*>(cb);
            bf16x8 a1 = *reinterpret_cast<const bf16x8*>(cb + 16 * 8);
            acc[0][0] = __builtin_amdgcn_mfma_f32_16x16x32_bf16(a0, Ball[2 * ks],     acc[0][0], 0, 0, 0);
            acc[0][1] = __builtin_amdgcn_mfma_f32_16x16x32_bf16(a0, Ball[2 * ks + 1], acc[0][1], 0, 0, 0);
            acc[1][0] = __builtin_amdgcn_mfma_f32_16x16x32_bf16(a1, Ball[2 * ks],     acc[1][0], 0, 0, 0);
            acc[1][1] = __builtin_amdgcn_mfma_f32_16x16x32_bf16(a1, Ball[2 * ks + 1], acc[1][1], 0, 0, 0);
        }
    }

    // epilogue: + bias + joint_feats
    float bv[2];
    bv[0] = bias[j * CJ + wave * 32 + r];
    bv[1] = bias[j * CJ + wave * 32 + 16 + r];

    #pragma unroll
    for (int mi = 0; mi < 2; ++mi) {
        #pragma unroll
        for (int rr = 0; rr < 4; ++rr) {
            const int bg = row0 + mi * 16 + q * 4 + rr;
            const size_t ob = ((size_t)bg * NJ + j) * CJ + wave * 32;
            #pragma unroll
            for (int ni = 0; ni < 2; ++ni) {
                const int o = ni * 16 + r;
                out[ob + o] = acc[mi][ni][rr] + bv[ni] + jf[ob + o];
            }
        }
    }
}

extern "C" void kernel_launch(void* const* d_in, const int* in_sizes, int n_in,
                              void* d_out, int out_size, void* d_ws, size_t ws_size,
                              hipStream_t stream) {
    (void)in_sizes; (void)n_in; (void)out_size; (void)d_ws; (void)ws_size;
    const float* link  = (const float*)d_in[0];
    const float* jfeat = (const float*)d_in[1];
    const float* W     = (const float*)d_in[2];
    const float* bias  = (const float*)d_in[3];
    const int*   child = (const int*)d_in[4];
    float* out = (float*)d_out;

    conv_w<<<dim3((NJ * KTOT * CJ / 8) / 256), dim3(256), 0, stream>>>(W);
    joint_gemm<<<dim3(NJ * (NB / BM)), dim3(256), 0, stream>>>(link, jfeat, bias, child, out);
}